// Round 11
// baseline (1406.592 us; speedup 1.0000x reference)
//
#include <hip/hip_runtime.h>
#include <hip/hip_cooperative_groups.h>

namespace cg = cooperative_groups;

#define NN 512       // nodes
#define BB_ 64       // batch
#define EE 32768     // edges
#define TT 50        // input channels
#define FF 32        // hidden channels
#define NB 2048      // BB_*FF

typedef _Float16 f16x8 __attribute__((ext_vector_type(8)));
typedef float    f32x4 __attribute__((ext_vector_type(4)));
typedef unsigned short ushort_t;

// ws float offsets
#define OFF_LHAT 0                          // 262144 f32
#define OFF_LHI  262144                     // 262144 u16
#define OFF_LLO  393216
#define OFF_DEG  524288                     // 512
#define OFF_HP0  524800                     // 1048576
#define OFF_HP1  1573376
#define OFF_GHT  2621952                    // 1048576 u16
#define OFF_GLT  3146240
#define OFF_F0   3670528                    // 1048576
#define OFF_P    4719104                    // 64*16384
#define WS_FLOATS 5767680

struct Params {
    const float* x; const int* ei; const float* ew;
    const float* cW[6]; const float* cb[6];
    const float* fc1W; const float* fc1b;
    const float* fc2W; const float* fc2b;
    const float* fc3W; const float* fc3b;
    float* ws; float* out;
};

union SM {
    struct { float W0s[TT * FF]; float W1s[TT * FF]; float bs[FF];
             float rows[64][TT + 1]; } s;
    struct { ushort_t Ah[2][64][40], Al[2][64][40],
                      Bh[2][64][40], Bl[2][64][40]; } p;
    struct { float AT[256][68]; } f1;
    struct { float row[256]; float r2[128]; } f23;
};

__device__ __forceinline__ unsigned us16(_Float16 h) {
    return (unsigned)__builtin_bit_cast(unsigned short, h);
}

// ---------------- setup phases (gid over 512*256 threads) ----------------

__device__ void ph_zero(float* ws, int gid) {
    float* Lhat = ws + OFF_LHAT;
    for (int i = gid; i < NN * NN; i += 131072) Lhat[i] = 0.f;
    if (gid < NN) ws[OFF_DEG + gid] = 0.f;
}

__device__ void ph_deg(const Params& p, int gid) {
    if (gid >= EE) return;
    int s = p.ei[gid] & (NN - 1), d = p.ei[EE + gid] & (NN - 1);
    if (s != d) atomicAdd(&p.ws[OFF_DEG + s], p.ew[gid]);
}

__device__ void ph_dinv(float* ws, int gid) {
    if (gid >= NN) return;
    float d = ws[OFF_DEG + gid];
    ws[OFF_DEG + gid] = (d > 0.f) ? rsqrtf(d) : 0.f;
}

__device__ void ph_build(const Params& p, int gid) {
    if (gid >= EE) return;
    int s = p.ei[gid] & (NN - 1), d = p.ei[EE + gid] & (NN - 1);
    if (s == d) return;
    float nm = -(p.ws[OFF_DEG + s] * p.ew[gid] * p.ws[OFF_DEG + d]);
    atomicAdd(&p.ws[OFF_LHAT + d * NN + s], nm);
}

__device__ void ph_split(float* ws, int gid) {
    ushort_t* Lhi = (ushort_t*)(ws + OFF_LHI);
    ushort_t* Llo = (ushort_t*)(ws + OFF_LLO);
    for (int i = gid; i < NN * NN; i += 131072) {
        float v = ws[OFF_LHAT + i];
        _Float16 h = (_Float16)v;
        _Float16 l = (_Float16)(v - (float)h);
        Lhi[i] = (ushort_t)us16(h);
        Llo[i] = (ushort_t)us16(l);
    }
}

// ---------------- small phase: Ght/Glt = split(H W1)^T, F0 = H W0 + b -----
// 512 blocks = (b 0..63) x (ngroup 0..7 of 64 nodes); thread = (f, nq of 8 nodes)
template<int CIN, int MODE>
__device__ void ph_small(SM& sm, const Params& p, int l, int bid, int tid) {
    float* ws = p.ws;
    const float* W  = p.cW[l];
    const float* A0 = (MODE == 0) ? p.x : ws + OFF_HP0;
    const float* A1 = ws + OFF_HP1;
    ushort_t* Ght = (ushort_t*)(ws + OFF_GHT);
    ushort_t* Glt = (ushort_t*)(ws + OFF_GLT);
    float* F0 = ws + OFF_F0;

    const int b = bid >> 3, n0 = (bid & 7) * 64;
    for (int i = tid; i < CIN * FF; i += 256) {
        sm.s.W0s[i] = W[i];
        sm.s.W1s[i] = W[CIN * FF + i];
    }
    if (tid < FF) sm.s.bs[tid] = p.cb[l][tid];
    if (MODE == 0) {
        const float* xb = A0 + ((size_t)b * NN + n0) * CIN;
        for (int idx = tid; idx < 64 * CIN; idx += 256)
            sm.s.rows[idx / CIN][idx % CIN] = xb[idx];
    } else {
        for (int q = tid; q < 64 * 8; q += 256) {
            int n = q >> 3, c4 = (q & 7) * 4;
            size_t o = (size_t)(n0 + n) * NB + b * FF + c4;
            float4 v0 = *(const float4*)&A0[o];
            float4 v1 = *(const float4*)&A1[o];
            sm.s.rows[n][c4 + 0] = fmaxf(v0.x + v1.x, 0.f);
            sm.s.rows[n][c4 + 1] = fmaxf(v0.y + v1.y, 0.f);
            sm.s.rows[n][c4 + 2] = fmaxf(v0.z + v1.z, 0.f);
            sm.s.rows[n][c4 + 3] = fmaxf(v0.w + v1.w, 0.f);
        }
    }
    __syncthreads();
    const int f = tid & 31, nq = tid >> 5;
    float gacc[8] = {};
    float facc[8];
#pragma unroll
    for (int i = 0; i < 8; ++i) facc[i] = sm.s.bs[f];
    for (int c = 0; c < CIN; ++c) {
        float w0 = sm.s.W0s[c * FF + f], w1 = sm.s.W1s[c * FF + f];
#pragma unroll
        for (int i = 0; i < 8; ++i) {
            float hv = sm.s.rows[nq * 8 + i][c];
            gacc[i] = fmaf(hv, w1, gacc[i]);
            facc[i] = fmaf(hv, w0, facc[i]);
        }
    }
    const int j = b * FF + f, kk = n0 + nq * 8;
#pragma unroll
    for (int i = 0; i < 8; ++i)
        F0[(size_t)(kk + i) * NB + j] = facc[i];
    unsigned hw[4], lw[4];
#pragma unroll
    for (int q2 = 0; q2 < 4; ++q2) {
        float v0 = gacc[2 * q2], v1 = gacc[2 * q2 + 1];
        _Float16 h0 = (_Float16)v0, h1 = (_Float16)v1;
        _Float16 l0 = (_Float16)(v0 - (float)h0), l1 = (_Float16)(v1 - (float)h1);
        hw[q2] = us16(h0) | (us16(h1) << 16);
        lw[q2] = us16(l0) | (us16(l1) << 16);
    }
    *(uint4*)&Ght[(size_t)j * NN + kk] = make_uint4(hw[0], hw[1], hw[2], hw[3]);
    *(uint4*)&Glt[(size_t)j * NN + kk] = make_uint4(lw[0], lw[1], lw[2], lw[3]);
}

// ---------------- prop phase: Hp_z = Lhat[:,zK..] @ G[zK..,:] (+F0 @ z0) ---
// 512 blocks = (jt 0..31, it 0..7, z 0..1); 4 waves (2x2 of 32x32), K-chunk 32.
__device__ void ph_prop(SM& sm, const Params& p, int bid, int tid) {
    float* ws = p.ws;
    const ushort_t* Lhi = (const ushort_t*)(ws + OFF_LHI);
    const ushort_t* Llo = (const ushort_t*)(ws + OFF_LLO);
    const ushort_t* Ght = (const ushort_t*)(ws + OFF_GHT);
    const ushort_t* Glt = (const ushort_t*)(ws + OFF_GLT);
    const float* F0 = ws + OFF_F0;

    const int z = bid & 1, it = (bid >> 1) & 7, jt = bid >> 4;
    const int i0 = it * 64, j0 = jt * 64, kbase = z * 256;
    const int lane = tid & 63, w = tid >> 6;
    const int wm = w >> 1, wn = w & 1;
    const int grp = lane >> 4, l16 = lane & 15;
    const int sr = tid >> 2, sk = (tid & 3) * 8;

    const ushort_t* pAh = Lhi + (size_t)(i0 + sr) * NN + kbase + sk;
    const ushort_t* pAl = Llo + (size_t)(i0 + sr) * NN + kbase + sk;
    const ushort_t* pBh = Ght + (size_t)(j0 + sr) * NN + kbase + sk;
    const ushort_t* pBl = Glt + (size_t)(j0 + sr) * NN + kbase + sk;

    f32x4 acc[2][2] = {};
    uint4 rah = *(const uint4*)pAh;
    uint4 ral = *(const uint4*)pAl;
    uint4 rbh = *(const uint4*)pBh;
    uint4 rbl = *(const uint4*)pBl;

    for (int t = 0; t < 8; ++t) {
        const int buf = t & 1;
        *(uint4*)&sm.p.Ah[buf][sr][sk] = rah;
        *(uint4*)&sm.p.Al[buf][sr][sk] = ral;
        *(uint4*)&sm.p.Bh[buf][sr][sk] = rbh;
        *(uint4*)&sm.p.Bl[buf][sr][sk] = rbl;
        __syncthreads();
        if (t < 7) {
            const int ko = (t + 1) * 32;
            rah = *(const uint4*)(pAh + ko);
            ral = *(const uint4*)(pAl + ko);
            rbh = *(const uint4*)(pBh + ko);
            rbl = *(const uint4*)(pBl + ko);
        }
        f16x8 ah[2], al[2], bh[2], bl[2];
#pragma unroll
        for (int mi = 0; mi < 2; ++mi) {
            ah[mi] = *(const f16x8*)&sm.p.Ah[buf][wm * 32 + mi * 16 + l16][grp * 8];
            al[mi] = *(const f16x8*)&sm.p.Al[buf][wm * 32 + mi * 16 + l16][grp * 8];
        }
#pragma unroll
        for (int ni = 0; ni < 2; ++ni) {
            bh[ni] = *(const f16x8*)&sm.p.Bh[buf][wn * 32 + ni * 16 + l16][grp * 8];
            bl[ni] = *(const f16x8*)&sm.p.Bl[buf][wn * 32 + ni * 16 + l16][grp * 8];
        }
#pragma unroll
        for (int mi = 0; mi < 2; ++mi)
#pragma unroll
            for (int ni = 0; ni < 2; ++ni) {
                acc[mi][ni] = __builtin_amdgcn_mfma_f32_16x16x32_f16(al[mi], bl[ni], acc[mi][ni], 0, 0, 0);
                acc[mi][ni] = __builtin_amdgcn_mfma_f32_16x16x32_f16(al[mi], bh[ni], acc[mi][ni], 0, 0, 0);
                acc[mi][ni] = __builtin_amdgcn_mfma_f32_16x16x32_f16(ah[mi], bl[ni], acc[mi][ni], 0, 0, 0);
                acc[mi][ni] = __builtin_amdgcn_mfma_f32_16x16x32_f16(ah[mi], bh[ni], acc[mi][ni], 0, 0, 0);
            }
        __syncthreads();
    }

    float* Hp = ws + (z ? OFF_HP1 : OFF_HP0);
#pragma unroll
    for (int mi = 0; mi < 2; ++mi)
#pragma unroll
        for (int ni = 0; ni < 2; ++ni)
#pragma unroll
            for (int q = 0; q < 4; ++q) {
                const int row = i0 + wm * 32 + mi * 16 + grp * 4 + q;
                const int col = j0 + wn * 32 + ni * 16 + l16;
                const size_t idx = (size_t)row * NB + col;
                float v = acc[mi][ni][q];
                if (z == 0) v += F0[idx];
                Hp[idx] = v;
            }
}

// ---------------- fc1 phase: P[kc][b][j] partials -------------------------
// 512 blocks = (jg 0..7, kc 0..63 of 8 nodes = 256 k-rows).
__device__ void ph_fc1(SM& sm, const Params& p, int bid, int tid) {
    float* ws = p.ws;
    const float* h0 = ws + OFF_HP0;
    const float* h1 = ws + OFF_HP1;
    float* P = ws + OFF_P;
    const int jg = bid & 7, kc = bid >> 3;
    const size_t base = (size_t)kc * 8 * NB;
#pragma unroll
    for (int i = 0; i < 16; ++i) {
        int q = tid + i * 256;             // float4 idx 0..4095
        float4 v0 = *(const float4*)&h0[base + q * 4];
        float4 v1 = *(const float4*)&h1[base + q * 4];
        int flat = q * 4;
        int nn2 = flat >> 11, rem = flat & 2047;
        int b = rem >> 5, f0 = rem & 31;
        int krow = nn2 * 32 + f0;
        sm.f1.AT[krow + 0][b] = v0.x + v1.x;
        sm.f1.AT[krow + 1][b] = v0.y + v1.y;
        sm.f1.AT[krow + 2][b] = v0.z + v1.z;
        sm.f1.AT[krow + 3][b] = v0.w + v1.w;
    }
    __syncthreads();
    const int tj = tid & 31, bq = tid >> 5;
    float acc[8] = {};
    const float* wp = p.fc1W + (size_t)(kc * 256) * 256 + jg * 32 + tj;
#pragma unroll 8
    for (int k = 0; k < 256; ++k) {
        float wv = wp[(size_t)k * 256];
        const float* ap = &sm.f1.AT[k][bq * 8];
        float4 a0 = *(const float4*)ap;
        float4 a1 = *(const float4*)(ap + 4);
        acc[0] = fmaf(a0.x, wv, acc[0]); acc[1] = fmaf(a0.y, wv, acc[1]);
        acc[2] = fmaf(a0.z, wv, acc[2]); acc[3] = fmaf(a0.w, wv, acc[3]);
        acc[4] = fmaf(a1.x, wv, acc[4]); acc[5] = fmaf(a1.y, wv, acc[5]);
        acc[6] = fmaf(a1.z, wv, acc[6]); acc[7] = fmaf(a1.w, wv, acc[7]);
    }
#pragma unroll
    for (int b2 = 0; b2 < 8; ++b2)
        P[(size_t)kc * 16384 + (bq * 8 + b2) * 256 + jg * 32 + tj] = acc[b2];
}

// ---------------- fc23 phase (first 64 blocks) ----------------------------
__device__ void ph_fc23(SM& sm, const Params& p, int bid, int tid) {
    if (bid >= BB_) return;
    const float* P = p.ws + OFF_P;
    const int m = bid;
    {
        float s = p.fc1b[tid];
#pragma unroll 8
        for (int kc = 0; kc < 64; ++kc)
            s += P[(size_t)kc * 16384 + m * 256 + tid];
        sm.f23.row[tid] = s;
    }
    __syncthreads();
    if (tid < 128) {
        float acc = p.fc2b[tid];
#pragma unroll 4
        for (int k = 0; k < 256; ++k)
            acc = fmaf(sm.f23.row[k], p.fc2W[k * 128 + tid], acc);
        sm.f23.r2[tid] = acc;
    }
    __syncthreads();
    if (tid < 128) {
        const int wv = tid >> 6, lv = tid & 63;
        float s2 = sm.f23.r2[lv] * p.fc3W[lv * 2 + wv]
                 + sm.f23.r2[lv + 64] * p.fc3W[(lv + 64) * 2 + wv];
#pragma unroll
        for (int off = 32; off > 0; off >>= 1)
            s2 += __shfl_down(s2, off);
        if (lv == 0) p.out[m * 2 + wv] = s2 + p.fc3b[wv];
    }
}

// ---------------- the cooperative mega-kernel ----------------------------

__global__ __launch_bounds__(256, 2) void k_mega(Params p) {
    cg::grid_group grid = cg::this_grid();
    __shared__ SM sm;
    const int tid = threadIdx.x, bid = blockIdx.x;
    const int gid = bid * 256 + tid;

    ph_zero(p.ws, gid);          grid.sync();
    ph_deg(p, gid);              grid.sync();
    ph_dinv(p.ws, gid);          grid.sync();
    ph_build(p, gid);            grid.sync();
    ph_split(p.ws, gid);         grid.sync();

    for (int l = 0; l < 6; ++l) {
        if (l == 0) ph_small<TT, 0>(sm, p, l, bid, tid);
        else        ph_small<FF, 1>(sm, p, l, bid, tid);
        grid.sync();
        ph_prop(sm, p, bid, tid);
        grid.sync();
    }
    ph_fc1(sm, p, bid, tid);     grid.sync();
    ph_fc23(sm, p, bid, tid);
}

// ---------------- fallback wrappers (if coop launch unavailable) ----------

__global__ __launch_bounds__(256) void k_s0(Params p) { ph_zero(p.ws, blockIdx.x * 256 + threadIdx.x); }
__global__ __launch_bounds__(256) void k_s1(Params p) { ph_deg(p, blockIdx.x * 256 + threadIdx.x); }
__global__ __launch_bounds__(256) void k_s2(Params p) { ph_dinv(p.ws, blockIdx.x * 256 + threadIdx.x); }
__global__ __launch_bounds__(256) void k_s3(Params p) { ph_build(p, blockIdx.x * 256 + threadIdx.x); }
__global__ __launch_bounds__(256) void k_s4(Params p) { ph_split(p.ws, blockIdx.x * 256 + threadIdx.x); }
__global__ __launch_bounds__(256) void k_sm0(Params p, int l) { __shared__ SM sm; ph_small<TT, 0>(sm, p, l, blockIdx.x, threadIdx.x); }
__global__ __launch_bounds__(256) void k_sm1(Params p, int l) { __shared__ SM sm; ph_small<FF, 1>(sm, p, l, blockIdx.x, threadIdx.x); }
__global__ __launch_bounds__(256) void k_pr(Params p)  { __shared__ SM sm; ph_prop(sm, p, blockIdx.x, threadIdx.x); }
__global__ __launch_bounds__(256) void k_f1(Params p)  { __shared__ SM sm; ph_fc1(sm, p, blockIdx.x, threadIdx.x); }
__global__ __launch_bounds__(256) void k_f23(Params p) { __shared__ SM sm; ph_fc23(sm, p, blockIdx.x, threadIdx.x); }

__global__ void k_zero_out(float* out, int n) {
    int i = blockIdx.x * blockDim.x + threadIdx.x;
    if (i < n) out[i] = 0.f;
}

// ---------------- launch ----------------

extern "C" void kernel_launch(void* const* d_in, const int* in_sizes, int n_in,
                              void* d_out, int out_size, void* d_ws, size_t ws_size,
                              hipStream_t stream) {
    float* outp = (float*)d_out;
    if (ws_size < (size_t)WS_FLOATS * sizeof(float)) {
        k_zero_out<<<(out_size + 255) / 256, 256, 0, stream>>>(outp, out_size);
        return;
    }

    Params p;
    p.x  = (const float*)d_in[0];
    p.ei = (const int*)d_in[1];
    p.ew = (const float*)d_in[2];
    for (int i = 0; i < 6; ++i) {
        p.cW[i] = (const float*)d_in[3 + 2 * i];
        p.cb[i] = (const float*)d_in[4 + 2 * i];
    }
    p.fc1W = (const float*)d_in[15]; p.fc1b = (const float*)d_in[16];
    p.fc2W = (const float*)d_in[17]; p.fc2b = (const float*)d_in[18];
    p.fc3W = (const float*)d_in[19]; p.fc3b = (const float*)d_in[20];
    p.ws = (float*)d_ws;
    p.out = outp;

    void* args[] = { (void*)&p };
    hipError_t err = hipLaunchCooperativeKernel((const void*)k_mega,
                                                dim3(512), dim3(256),
                                                args, 0, stream);
    if (err != hipSuccess) {
        // fallback: same phases as ordinary kernels
        k_s0<<<512, 256, 0, stream>>>(p);
        k_s1<<<512, 256, 0, stream>>>(p);
        k_s2<<<512, 256, 0, stream>>>(p);
        k_s3<<<512, 256, 0, stream>>>(p);
        k_s4<<<512, 256, 0, stream>>>(p);
        for (int l = 0; l < 6; ++l) {
            if (l == 0) k_sm0<<<512, 256, 0, stream>>>(p, l);
            else        k_sm1<<<512, 256, 0, stream>>>(p, l);
            k_pr<<<512, 256, 0, stream>>>(p);
        }
        k_f1<<<512, 256, 0, stream>>>(p);
        k_f23<<<512, 256, 0, stream>>>(p);
    }
}

// Round 13
// 358.382 us; speedup vs baseline: 3.9248x; 3.9248x over previous
//
#include <hip/hip_runtime.h>

#define NN 512       // nodes
#define BB_ 64       // batch
#define EE 32768     // edges
#define TT 50        // input channels
#define FF 32        // hidden channels
#define NB 2048      // BB_*FF
#define QN 128       // nodes per k-quarter
#define GSTR 136     // G row stride (u16): 128 + 8 pad, keeps b128 16B-aligned

typedef _Float16 f16x8 __attribute__((ext_vector_type(8)));
typedef float    f32x4 __attribute__((ext_vector_type(4)));
typedef unsigned short u16t;

// ws float offsets
#define OFF_LHAT 0                     // 262144
#define OFF_LHI  262144                // u16 plane, 131072 floats
#define OFF_LLO  393216
#define OFF_DEG  524288                // 512
#define NPLANE   (NN * NB)             // 1048576
#define OFF_HPA  524800                // 4 partial planes (in)
#define OFF_HPB  (OFF_HPA + 4 * NPLANE)
#define OFF_P    (OFF_HPB + 4 * NPLANE)
#define WS_FLOATS (OFF_P + 128 * 16384)

__device__ __forceinline__ void fsplit(float v, u16t& h, u16t& l) {
    _Float16 hh = (_Float16)v;
    _Float16 ll = (_Float16)(v - (float)hh);
    h = __builtin_bit_cast(u16t, hh);
    l = __builtin_bit_cast(u16t, ll);
}

// ---------------- setup kernels ----------------

__global__ void k_zero_out(float* out, int n) {
    int i = blockIdx.x * blockDim.x + threadIdx.x;
    if (i < n) out[i] = 0.f;
}

__global__ void k_zero_range(float* p, int n) {
    int i = blockIdx.x * blockDim.x + threadIdx.x;
    if (i < n) p[i] = 0.f;
}

__global__ void k_deg(const int* __restrict__ ei, const float* __restrict__ ew,
                      float* __restrict__ deg) {
    int e = blockIdx.x * blockDim.x + threadIdx.x;
    if (e >= EE) return;
    int s = ei[e] & (NN - 1), d = ei[EE + e] & (NN - 1);
    if (s != d) atomicAdd(&deg[s], ew[e]);
}

__global__ void k_dinv(float* deg) {
    int i = threadIdx.x;
    float d = deg[i];
    deg[i] = (d > 0.f) ? rsqrtf(d) : 0.f;
}

__global__ void k_build(const int* __restrict__ ei, const float* __restrict__ ew,
                        const float* __restrict__ dinv, float* __restrict__ Lhat) {
    int e = blockIdx.x * blockDim.x + threadIdx.x;
    if (e >= EE) return;
    int s = ei[e] & (NN - 1), d = ei[EE + e] & (NN - 1);
    if (s == d) return;
    float nm = -(dinv[s] * ew[e] * dinv[d]);
    atomicAdd(&Lhat[d * NN + s], nm);
}

__global__ void k_splitL(const float* __restrict__ L,
                         u16t* __restrict__ Lhi, u16t* __restrict__ Llo) {
    int i = blockIdx.x * 256 + threadIdx.x;
    u16t h, l;
    fsplit(L[i], h, l);
    Lhi[i] = h; Llo[i] = l;
}

// ---------------- fused ChebConv layer ----------------
// block = (b, it, z): 1024 blocks, 256 thr = 4 waves (2x2 of 64x16 sub-tiles).
// Stages H k-quarter z (MODE1: relu(sum of 4 in-planes)), computes
// G = Hq @ W1 via MFMA in LDS, seeds acc with F0+bias (it==z only), then
// acc += Lhat[stripe it, quarter z] @ G.  Writes out-plane z (partial).
template<int CIN, int CINP, int MODE>
__global__ __launch_bounds__(256) void k_layer(
        const float* __restrict__ Xin, const float* __restrict__ Hin,
        const u16t* __restrict__ Lhi, const u16t* __restrict__ Llo,
        const float* __restrict__ W, const float* __restrict__ bias,
        float* __restrict__ Hout) {
    __shared__ u16t Hh[QN][CINP], Hl[QN][CINP];
    __shared__ u16t Gh[FF][GSTR], Gl[FF][GSTR];
    __shared__ u16t W1h[FF][CINP], W1l[FF][CINP];
    __shared__ float bs[FF];
    const int tid = threadIdx.x, bid = blockIdx.x;
    const int b = bid >> 4, it = (bid >> 2) & 3, z = bid & 3;
    const int lane = tid & 63, w = tid >> 6;
    const int wm = w >> 1, wn = w & 1;
    const int grp = lane >> 4, l16 = lane & 15;

    // ---- stage H quarter z as f16 hi/lo ----
    if (MODE == 0) {
        for (int idx = tid; idx < QN * CINP; idx += 256) {
            int node = idx / CINP, c = idx % CINP;
            float v = (c < CIN)
                ? Xin[((size_t)b * NN + z * QN + node) * CIN + c] : 0.f;
            fsplit(v, Hh[node][c], Hl[node][c]);
        }
    } else {
        const float* p0 = Hin;
        const float* p1 = Hin + NPLANE;
        const float* p2 = Hin + 2 * NPLANE;
        const float* p3 = Hin + 3 * NPLANE;
#pragma unroll
        for (int i = 0; i < 4; ++i) {
            int q = tid + i * 256;              // float4 id, 1024 total
            int node = q >> 3, c4 = (q & 7) * 4;
            size_t o = (size_t)(z * QN + node) * NB + b * FF + c4;
            float4 v0 = *(const float4*)&p0[o];
            float4 v1 = *(const float4*)&p1[o];
            float4 v2 = *(const float4*)&p2[o];
            float4 v3 = *(const float4*)&p3[o];
            float vv[4] = { fmaxf(v0.x + v1.x + v2.x + v3.x, 0.f),
                            fmaxf(v0.y + v1.y + v2.y + v3.y, 0.f),
                            fmaxf(v0.z + v1.z + v2.z + v3.z, 0.f),
                            fmaxf(v0.w + v1.w + v2.w + v3.w, 0.f) };
            ushort4 hh, ll;
            fsplit(vv[0], hh.x, ll.x); fsplit(vv[1], hh.y, ll.y);
            fsplit(vv[2], hh.z, ll.z); fsplit(vv[3], hh.w, ll.w);
            *(ushort4*)&Hh[node][c4] = hh;
            *(ushort4*)&Hl[node][c4] = ll;
        }
    }
    // ---- stage W1 transposed [fout][cin], zero-padded ----
    for (int idx = tid; idx < FF * CINP; idx += 256) {
        int f = idx & 31, c = idx >> 5;
        float v = (c < CIN) ? W[(size_t)CIN * FF + c * FF + f] : 0.f;
        fsplit(v, W1h[f][c], W1l[f][c]);
    }
    if (tid < FF) bs[tid] = bias[tid];
    __syncthreads();

    // ---- G = Hq @ W1 via MFMA (4-product split) ----
    f32x4 accg[2][2] = {};
#pragma unroll
    for (int kc = 0; kc < CINP / 32; ++kc) {
        f16x8 gbh[2], gbl[2], gah[2], gal[2];
#pragma unroll
        for (int nt = 0; nt < 2; ++nt) {
            gbh[nt] = *(const f16x8*)&W1h[nt * 16 + l16][kc * 32 + grp * 8];
            gbl[nt] = *(const f16x8*)&W1l[nt * 16 + l16][kc * 32 + grp * 8];
        }
#pragma unroll
        for (int mi = 0; mi < 2; ++mi) {
            gah[mi] = *(const f16x8*)&Hh[w * 32 + mi * 16 + l16][kc * 32 + grp * 8];
            gal[mi] = *(const f16x8*)&Hl[w * 32 + mi * 16 + l16][kc * 32 + grp * 8];
        }
#pragma unroll
        for (int mi = 0; mi < 2; ++mi)
#pragma unroll
            for (int nt = 0; nt < 2; ++nt) {
                accg[mi][nt] = __builtin_amdgcn_mfma_f32_16x16x32_f16(gal[mi], gbl[nt], accg[mi][nt], 0, 0, 0);
                accg[mi][nt] = __builtin_amdgcn_mfma_f32_16x16x32_f16(gal[mi], gbh[nt], accg[mi][nt], 0, 0, 0);
                accg[mi][nt] = __builtin_amdgcn_mfma_f32_16x16x32_f16(gah[mi], gbl[nt], accg[mi][nt], 0, 0, 0);
                accg[mi][nt] = __builtin_amdgcn_mfma_f32_16x16x32_f16(gah[mi], gbh[nt], accg[mi][nt], 0, 0, 0);
            }
    }
    // store G planes [fout][node-in-quarter]  (C layout: col=l16, row=grp*4+q)
#pragma unroll
    for (int mi = 0; mi < 2; ++mi)
#pragma unroll
        for (int nt = 0; nt < 2; ++nt) {
            ushort4 hh, ll;
            fsplit(accg[mi][nt][0], hh.x, ll.x);
            fsplit(accg[mi][nt][1], hh.y, ll.y);
            fsplit(accg[mi][nt][2], hh.z, ll.z);
            fsplit(accg[mi][nt][3], hh.w, ll.w);
            int node = w * 32 + mi * 16 + grp * 4;
            int f = nt * 16 + l16;
            *(ushort4*)&Gh[f][node] = hh;
            *(ushort4*)&Gl[f][node] = ll;
        }
    __syncthreads();

    // ---- acc seed: F0 = Hq W0 (+bias later), only stripe-owning blocks ----
    f32x4 acc[4] = {};
    if (it == z) {
#pragma unroll
        for (int kc = 0; kc < CINP / 32; ++kc) {
            f16x8 w0h, w0l;
#pragma unroll
            for (int j = 0; j < 8; ++j) {
                int c = kc * 32 + grp * 8 + j;
                float v = (c < CIN) ? W[(size_t)c * FF + wn * 16 + l16] : 0.f;
                _Float16 hh = (_Float16)v;
                w0h[j] = hh;
                w0l[j] = (_Float16)(v - (float)hh);
            }
#pragma unroll
            for (int mi = 0; mi < 4; ++mi) {
                f16x8 ah = *(const f16x8*)&Hh[wm * 64 + mi * 16 + l16][kc * 32 + grp * 8];
                f16x8 al = *(const f16x8*)&Hl[wm * 64 + mi * 16 + l16][kc * 32 + grp * 8];
                acc[mi] = __builtin_amdgcn_mfma_f32_16x16x32_f16(al, w0l, acc[mi], 0, 0, 0);
                acc[mi] = __builtin_amdgcn_mfma_f32_16x16x32_f16(al, w0h, acc[mi], 0, 0, 0);
                acc[mi] = __builtin_amdgcn_mfma_f32_16x16x32_f16(ah, w0l, acc[mi], 0, 0, 0);
                acc[mi] = __builtin_amdgcn_mfma_f32_16x16x32_f16(ah, w0h, acc[mi], 0, 0, 0);
            }
        }
    }

    // ---- big GEMM: Lhat[stripe it, quarter z] @ G ----
    const int i0 = it * QN;
#pragma unroll
    for (int kc = 0; kc < 4; ++kc) {
        f16x8 bh = *(const f16x8*)&Gh[wn * 16 + l16][kc * 32 + grp * 8];
        f16x8 bl = *(const f16x8*)&Gl[wn * 16 + l16][kc * 32 + grp * 8];
#pragma unroll
        for (int mi = 0; mi < 4; ++mi) {
            size_t ao = (size_t)(i0 + wm * 64 + mi * 16 + l16) * NN
                      + z * QN + kc * 32 + grp * 8;
            f16x8 ah = *(const f16x8*)(Lhi + ao);
            f16x8 al = *(const f16x8*)(Llo + ao);
            acc[mi] = __builtin_amdgcn_mfma_f32_16x16x32_f16(al, bl, acc[mi], 0, 0, 0);
            acc[mi] = __builtin_amdgcn_mfma_f32_16x16x32_f16(al, bh, acc[mi], 0, 0, 0);
            acc[mi] = __builtin_amdgcn_mfma_f32_16x16x32_f16(ah, bl, acc[mi], 0, 0, 0);
            acc[mi] = __builtin_amdgcn_mfma_f32_16x16x32_f16(ah, bh, acc[mi], 0, 0, 0);
        }
    }

    // ---- epilogue: write partial out-plane z ----
    float* Hp = Hout + (size_t)z * NPLANE;
    const float bterm = (it == z) ? bs[wn * 16 + l16] : 0.f;
#pragma unroll
    for (int mi = 0; mi < 4; ++mi)
#pragma unroll
        for (int q = 0; q < 4; ++q) {
            int row = i0 + wm * 64 + mi * 16 + grp * 4 + q;
            Hp[(size_t)row * NB + b * FF + wn * 16 + l16] = acc[mi][q] + bterm;
        }
}

// ---------------- FC1: A(64x16384) @ W(16384x256), K-split partials ---------
// A = sum of 4 planes (no relu after conv6). grid (8 jg, 128 kc of 4 nodes).
__global__ __launch_bounds__(256) void k_fc1(const float* __restrict__ hp,
                                             const float* __restrict__ W,
                                             float* __restrict__ P) {
    __shared__ float AT[128][68];      // AT[k][b]
    const int tid = threadIdx.x;
    const int jg = blockIdx.x;
    const int kc = blockIdx.y;
    const size_t base = (size_t)kc * 4 * NB;
    const float* p0 = hp;
    const float* p1 = hp + NPLANE;
    const float* p2 = hp + 2 * NPLANE;
    const float* p3 = hp + 3 * NPLANE;
#pragma unroll
    for (int i = 0; i < 8; ++i) {
        int q = tid + i * 256;
        float4 v0 = *(const float4*)&p0[base + q * 4];
        float4 v1 = *(const float4*)&p1[base + q * 4];
        float4 v2 = *(const float4*)&p2[base + q * 4];
        float4 v3 = *(const float4*)&p3[base + q * 4];
        int flat = q * 4;
        int nn2 = flat >> 11, rem = flat & 2047;
        int b = rem >> 5, f0 = rem & 31;
        int krow = nn2 * 32 + f0;
        AT[krow + 0][b] = v0.x + v1.x + v2.x + v3.x;
        AT[krow + 1][b] = v0.y + v1.y + v2.y + v3.y;
        AT[krow + 2][b] = v0.z + v1.z + v2.z + v3.z;
        AT[krow + 3][b] = v0.w + v1.w + v2.w + v3.w;
    }
    __syncthreads();
    const int tj = tid & 31, bq = tid >> 5;
    float acc[8] = {};
    const float* wp = W + (size_t)(kc * 128) * 256 + jg * 32 + tj;
#pragma unroll 8
    for (int k = 0; k < 128; ++k) {
        float wv = wp[(size_t)k * 256];
        const float* ap = &AT[k][bq * 8];
        float4 a0 = *(const float4*)ap;
        float4 a1 = *(const float4*)(ap + 4);
        acc[0] = fmaf(a0.x, wv, acc[0]); acc[1] = fmaf(a0.y, wv, acc[1]);
        acc[2] = fmaf(a0.z, wv, acc[2]); acc[3] = fmaf(a0.w, wv, acc[3]);
        acc[4] = fmaf(a1.x, wv, acc[4]); acc[5] = fmaf(a1.y, wv, acc[5]);
        acc[6] = fmaf(a1.z, wv, acc[6]); acc[7] = fmaf(a1.w, wv, acc[7]);
    }
#pragma unroll
    for (int b2 = 0; b2 < 8; ++b2)
        P[(size_t)kc * 16384 + (bq * 8 + b2) * 256 + jg * 32 + tj] = acc[b2];
}

// ---------------- fused reduce + FC2 + FC3 ----------------
__global__ __launch_bounds__(128) void k_fc23(const float* __restrict__ P,
        const float* __restrict__ b1, const float* __restrict__ W2,
        const float* __restrict__ b2, const float* __restrict__ W3,
        const float* __restrict__ b3, float* __restrict__ out) {
    __shared__ float row[256];
    __shared__ float r2[128];
    const int m = blockIdx.x, j = threadIdx.x;
#pragma unroll
    for (int rep = 0; rep < 2; ++rep) {
        int k2 = j + rep * 128;
        float s = b1[k2];
#pragma unroll 8
        for (int kc = 0; kc < 128; ++kc)
            s += P[(size_t)kc * 16384 + m * 256 + k2];
        row[k2] = s;
    }
    __syncthreads();
    float acc = b2[j];
#pragma unroll 4
    for (int k = 0; k < 256; ++k)
        acc = fmaf(row[k], W2[k * 128 + j], acc);
    r2[j] = acc;
    __syncthreads();
    const int w = j >> 6, l = j & 63;
    float s2 = r2[l] * W3[l * 2 + w] + r2[l + 64] * W3[(l + 64) * 2 + w];
#pragma unroll
    for (int off = 32; off > 0; off >>= 1)
        s2 += __shfl_down(s2, off);
    if (l == 0) out[m * 2 + w] = s2 + b3[w];
}

// ---------------- launch ----------------

extern "C" void kernel_launch(void* const* d_in, const int* in_sizes, int n_in,
                              void* d_out, int out_size, void* d_ws, size_t ws_size,
                              hipStream_t stream) {
    float* outp = (float*)d_out;
    if (ws_size < (size_t)WS_FLOATS * sizeof(float)) {
        k_zero_out<<<(out_size + 255) / 256, 256, 0, stream>>>(outp, out_size);
        return;
    }

    const float* x  = (const float*)d_in[0];
    const int*   ei = (const int*)d_in[1];
    const float* ew = (const float*)d_in[2];
    const float* cW[6] = {(const float*)d_in[3], (const float*)d_in[5],
                          (const float*)d_in[7], (const float*)d_in[9],
                          (const float*)d_in[11], (const float*)d_in[13]};
    const float* cb[6] = {(const float*)d_in[4], (const float*)d_in[6],
                          (const float*)d_in[8], (const float*)d_in[10],
                          (const float*)d_in[12], (const float*)d_in[14]};
    const float* fc1W = (const float*)d_in[15];
    const float* fc1b = (const float*)d_in[16];
    const float* fc2W = (const float*)d_in[17];
    const float* fc2b = (const float*)d_in[18];
    const float* fc3W = (const float*)d_in[19];
    const float* fc3b = (const float*)d_in[20];

    float* ws   = (float*)d_ws;
    float* Lhat = ws + OFF_LHAT;
    u16t*  Lhi  = (u16t*)(ws + OFF_LHI);
    u16t*  Llo  = (u16t*)(ws + OFF_LLO);
    float* deg  = ws + OFF_DEG;
    float* HA   = ws + OFF_HPA;
    float* HB   = ws + OFF_HPB;
    float* P    = ws + OFF_P;

    // build dense Lhat, split to u16 planes
    k_zero_range<<<(OFF_DEG + 512 + 255) / 256, 256, 0, stream>>>(ws, OFF_DEG + 512);
    k_deg<<<EE / 256, 256, 0, stream>>>(ei, ew, deg);
    k_dinv<<<1, 512, 0, stream>>>(deg);
    k_build<<<EE / 256, 256, 0, stream>>>(ei, ew, deg, Lhat);
    k_splitL<<<NN * NN / 256, 256, 0, stream>>>(Lhat, Lhi, Llo);

    // 6 fused layers (planes ping-pong A<->B)
    k_layer<TT, 64, 0><<<1024, 256, 0, stream>>>(x,  nullptr, Lhi, Llo, cW[0], cb[0], HA);
    k_layer<FF, 32, 1><<<1024, 256, 0, stream>>>(nullptr, HA, Lhi, Llo, cW[1], cb[1], HB);
    k_layer<FF, 32, 1><<<1024, 256, 0, stream>>>(nullptr, HB, Lhi, Llo, cW[2], cb[2], HA);
    k_layer<FF, 32, 1><<<1024, 256, 0, stream>>>(nullptr, HA, Lhi, Llo, cW[3], cb[3], HB);
    k_layer<FF, 32, 1><<<1024, 256, 0, stream>>>(nullptr, HB, Lhi, Llo, cW[4], cb[4], HA);
    k_layer<FF, 32, 1><<<1024, 256, 0, stream>>>(nullptr, HA, Lhi, Llo, cW[5], cb[5], HB);

    // FC head (fc1 sums the 4 planes of HB; no relu — matches reference)
    dim3 fgrid(8, 128);
    k_fc1<<<fgrid, 256, 0, stream>>>(HB, fc1W, P);
    k_fc23<<<64, 128, 0, stream>>>(P, fc1b, fc2W, fc2b, fc3W, fc3b, outp);
}